// Round 15
// baseline (86.020 us; speedup 1.0000x reference)
//
#include <hip/hip_runtime.h>
#include <hip/hip_bf16.h>

#define B 16
#define S 4096
#define D 256
#define U 256
#define ROWS 64
#define NCHK (S / ROWS)  // 64 chunks per batch
#define CPB 2            // chunks per block (pipelined)

typedef short short8 __attribute__((ext_vector_type(8)));
typedef float f32x4 __attribute__((ext_vector_type(4)));

__device__ __forceinline__ ushort f2bf(float f) {
    union { float f; uint u; } x{f};
    uint r = (x.u + 0x7fffu + ((x.u >> 16) & 1u)) >> 16;  // RNE
    return (ushort)r;
}

__device__ __forceinline__ float fast_tanh(float x) {
    float e = __expf(2.0f * x);
    return 1.0f - 2.0f * __builtin_amdgcn_rcpf(e + 1.0f);
}

// KA: setup. blocks 0..15: pqb GEMV (ILP-parallel); blocks 16..23: W1 pack.
__global__ void ka_setup(const float* __restrict__ query, const float* __restrict__ W2,
                         const float* __restrict__ b2, const float* __restrict__ b1,
                         const float* __restrict__ W1, float* __restrict__ pqb,
                         ushort* __restrict__ W1p) {
    __shared__ float pp[4][U];
    int bid = blockIdx.x, t = threadIdx.x;
    if (bid < 16) {
        const float* qb = query + bid * D;
        int u0 = (t & 63) * 4, dc = t >> 6;
        float4 a = {0.f, 0.f, 0.f, 0.f};
#pragma unroll 16
        for (int i = 0; i < 64; ++i) {
            int d = dc * 64 + i;
            float qd = qb[d];
            float4 wv = *(const float4*)&W2[d * U + u0];
            a.x = fmaf(qd, wv.x, a.x);
            a.y = fmaf(qd, wv.y, a.y);
            a.z = fmaf(qd, wv.z, a.z);
            a.w = fmaf(qd, wv.w, a.w);
        }
        *(float4*)&pp[dc][u0] = a;
        __syncthreads();
        pqb[bid * U + t] = pp[0][t] + pp[1][t] + pp[2][t] + pp[3][t] + b2[t] + b1[t];
    } else {
        int kk = bid - 16;
        int l = t & 63, g = t >> 6;
        int colu0 = l & 15;
        int k0 = kk * 32 + (l >> 4) * 8;
#pragma unroll
        for (int i = 0; i < 4; ++i) {
            int nt = g * 4 + i;
            int colu = nt * 16 + colu0;
            ushort* dst = W1p + (((nt * 8) + kk) * 64 + l) * 8;
#pragma unroll
            for (int e = 0; e < 8; ++e) dst[e] = f2bf(W1[(k0 + e) * U + colu]);
        }
    }
}

// KB: 512 blocks x CPB=2 chunks, double-buffered LDS pipeline.
// Spill-proofed: prefetch loads for chunk c+1 are issued AFTER the epilogue
// consumes acc (register lifetimes swap instead of stacking); converted tile
// is written to the other LDS buffer after the cpart pass.
__global__ __launch_bounds__(256, 2) void kb_scores(
    const float* __restrict__ values, const ushort* __restrict__ W1p,
    const float* __restrict__ pqb, const float* __restrict__ V,
    const float* __restrict__ bV, float* __restrict__ scores,
    float* __restrict__ cstats, float* __restrict__ cpart) {
    __shared__ ushort Alds[2][ROWS * 256];  // 2 x 32 KB, XOR-swizzled
    __shared__ float red[4][ROWS];
    __shared__ float wch[ROWS];
    const int t = threadIdx.x;
    const int w = t >> 6, l = t & 63;
    const int lrow = l & 15, lk = l >> 4;
    const int chunk0 = blockIdx.x * CPB;
    const int b = chunk0 >> 6;  // CPB chunks never straddle a batch

    float bb[4], vv[4];
#pragma unroll
    for (int nt = 0; nt < 4; ++nt) {
        int u = (w * 4 + nt) * 16 + lrow;
        bb[nt] = pqb[b * U + u];
        vv[nt] = V[u];
    }
    const float bV0 = bV[0];

    float4 vreg[16];
    // prologue: stage chunk0 -> buf0
    {
        const float* src = values + ((size_t)(b * S + (chunk0 & 63) * ROWS)) * D;
#pragma unroll
        for (int i = 0; i < 16; ++i)
            vreg[i] = *(const float4*)&src[(i * 4 + w) * 256 + l * 4];
        char* lds0 = (char*)Alds[0];
#pragma unroll
        for (int i = 0; i < 16; ++i) {
            int row = i * 4 + w;
            ushort4 h;
            h.x = f2bf(vreg[i].x); h.y = f2bf(vreg[i].y);
            h.z = f2bf(vreg[i].z); h.w = f2bf(vreg[i].w);
            int byte = (row * 512 + l * 8) ^ ((row & 7) << 4);
            *(ushort4*)(lds0 + byte) = h;
        }
    }

    for (int c = 0; c < CPB; ++c) {
        const int chunk = chunk0 + c;
        const int s0 = (chunk & 63) * ROWS;
        char* lds = (char*)Alds[c & 1];
        __syncthreads();  // buf[c] ready (prologue or prior iteration's write)

        // ---- MFMA scores ----
        f32x4 acc[4][4];
#pragma unroll
        for (int mt = 0; mt < 4; ++mt)
#pragma unroll
            for (int nt = 0; nt < 4; ++nt) acc[mt][nt] = (f32x4){0.f, 0.f, 0.f, 0.f};

#pragma unroll
        for (int kk = 0; kk < 8; ++kk) {
            short8 afr[4], bfr[4];
#pragma unroll
            for (int nt = 0; nt < 4; ++nt)
                bfr[nt] = *(const short8*)&W1p[((((w * 4 + nt) * 8) + kk) * 64 + l) * 8];
#pragma unroll
            for (int mt = 0; mt < 4; ++mt) {
                int row = mt * 16 + lrow;
                int byte = (row * 512 + kk * 64 + lk * 16) ^ ((row & 7) << 4);
                afr[mt] = *(const short8*)(lds + byte);
            }
#pragma unroll
            for (int mt = 0; mt < 4; ++mt)
#pragma unroll
                for (int nt = 0; nt < 4; ++nt)
                    acc[mt][nt] = __builtin_amdgcn_mfma_f32_16x16x32_bf16(
                        afr[mt], bfr[nt], acc[mt][nt], 0, 0, 0);
        }

        // ---- epilogue: tanh, .V, reduce over u (consumes acc) ----
#pragma unroll
        for (int mt = 0; mt < 4; ++mt) {
#pragma unroll
            for (int r = 0; r < 4; ++r) {
                float s = 0.f;
#pragma unroll
                for (int nt = 0; nt < 4; ++nt)
                    s += fast_tanh(acc[mt][nt][r] + bb[nt]) * vv[nt];
                s += __shfl_xor(s, 1);
                s += __shfl_xor(s, 2);
                s += __shfl_xor(s, 4);
                s += __shfl_xor(s, 8);
                if (lrow == 0) red[w][mt * 16 + lk * 4 + r] = s;
            }
        }

        // issue next chunk's loads now (acc dead, vreg takes its registers);
        // they stream during stats + cpart below
        if (c + 1 < CPB) {
            const float* src =
                values + ((size_t)(b * S + ((chunk + 1) & 63) * ROWS)) * D;
#pragma unroll
            for (int i = 0; i < 16; ++i)
                vreg[i] = *(const float4*)&src[(i * 4 + w) * 256 + l * 4];
        }
        __syncthreads();

        if (t < ROWS) {  // wave 0: scores + chunk stats
            float s = red[0][t] + red[1][t] + red[2][t] + red[3][t] + bV0;
            scores[b * S + s0 + t] = s;
            float m = s;
#pragma unroll
            for (int off = 32; off; off >>= 1) m = fmaxf(m, __shfl_xor(m, off));
            float z0 = __expf(s - m);
            wch[t] = z0;
            float z = z0;
#pragma unroll
            for (int off = 32; off; off >>= 1) z += __shfl_xor(z, off);
            if (t == 0) {
                cstats[2 * chunk] = m;
                cstats[2 * chunk + 1] = z;
            }
        }
        __syncthreads();

        // ---- partial context from bf16 LDS: thread t owns column t ----
        union { uint i; float f; } cv;
        float cacc = 0.f;
#pragma unroll 8
        for (int r = 0; r < ROWS; ++r) {
            int byte = (r * 512 + t * 2) ^ ((r & 7) << 4);
            ushort u = *(const ushort*)(lds + byte);
            cv.i = (uint)u << 16;
            cacc = fmaf(wch[r], cv.f, cacc);
        }
        cpart[(size_t)chunk * D + t] = cacc;

        // write next chunk's tile into the other buffer (loads have landed)
        if (c + 1 < CPB) {
            char* ldsn = (char*)Alds[(c + 1) & 1];
#pragma unroll
            for (int i = 0; i < 16; ++i) {
                int row = i * 4 + w;
                ushort4 h;
                h.x = f2bf(vreg[i].x); h.y = f2bf(vreg[i].y);
                h.z = f2bf(vreg[i].z); h.w = f2bf(vreg[i].w);
                int byte = (row * 512 + l * 8) ^ ((row & 7) << 4);
                *(ushort4*)(ldsn + byte) = h;
            }
        }
        // loop-top __syncthreads publishes buf[(c+1)&1]
    }
}

// KC: finisher. 4 blocks per batch (q = quarter). (r13 verbatim)
__global__ void kc_final(const float* __restrict__ scores, const float* __restrict__ cstats,
                         const float* __restrict__ cpart, float* __restrict__ wout,
                         float* __restrict__ ctx) {
    __shared__ float scl[NCHK];
    __shared__ float stats[2];
    __shared__ float part[4][64];
    int b = blockIdx.x >> 2, q = blockIdx.x & 3;
    int t = threadIdx.x;

    if (t < 64) {
        float m = cstats[2 * (b * NCHK + t)];
        float z = cstats[2 * (b * NCHK + t) + 1];
        float M = m;
#pragma unroll
        for (int off = 32; off; off >>= 1) M = fmaxf(M, __shfl_xor(M, off));
        float zz = z * __expf(m - M);
#pragma unroll
        for (int off = 32; off; off >>= 1) zz += __shfl_xor(zz, off);
        scl[t] = __expf(m - M);
        if (t == 0) { stats[0] = M; stats[1] = zz; }
    }
    __syncthreads();
    float M = stats[0];
    float invZ = 1.0f / stats[1];

    int tq = t >> 6, dl = t & 63;
    int d = q * 64 + dl;
    float acc = 0.f;
#pragma unroll
    for (int i = 0; i < 16; ++i) {
        int c = tq * 16 + i;
        acc = fmaf(scl[c], cpart[(size_t)(b * NCHK + c) * D + d], acc);
    }
    part[tq][dl] = acc;

#pragma unroll
    for (int i = 0; i < 4; ++i) {
        int s = q * 1024 + i * 256 + t;
        wout[b * S + s] = __expf(scores[b * S + s] - M) * invZ;
    }
    __syncthreads();
    if (t < 64)
        ctx[b * D + q * 64 + t] =
            (part[0][t] + part[1][t] + part[2][t] + part[3][t]) * invZ;
}

extern "C" void kernel_launch(void* const* d_in, const int* in_sizes, int n_in,
                              void* d_out, int out_size, void* d_ws, size_t ws_size,
                              hipStream_t stream) {
    const float* values = (const float*)d_in[0];
    const float* query  = (const float*)d_in[1];
    const float* W1     = (const float*)d_in[2];
    const float* b1     = (const float*)d_in[3];
    const float* W2     = (const float*)d_in[4];
    const float* b2     = (const float*)d_in[5];
    const float* V      = (const float*)d_in[6];
    const float* bV     = (const float*)d_in[7];

    float* out  = (float*)d_out;
    float* ctx  = out;          // [B, D]
    float* wout = out + B * D;  // [B, S, 1]

    float* ws     = (float*)d_ws;
    float* pqb    = ws;                 // B*U          = 4096
    float* scores = pqb + B * U;        // B*S          = 65536
    float* cstats = scores + B * S;     // 2*B*NCHK     = 2048
    float* cpart  = cstats + 2048;      // B*NCHK*D     = 262144
    ushort* W1p   = (ushort*)(cpart + B * NCHK * D);  // 65536 ushorts

    ka_setup<<<24, 256, 0, stream>>>(query, W2, b2, b1, W1, pqb, W1p);
    kb_scores<<<B * NCHK / CPB, 256, 0, stream>>>(values, W1p, pqb, V, bV,
                                                  scores, cstats, cpart);
    kc_final<<<B * 4, 256, 0, stream>>>(scores, cstats, cpart, wout, ctx);
}

// Round 16
// 55.246 us; speedup vs baseline: 1.5571x; 1.5571x over previous
//
#include <hip/hip_runtime.h>
#include <hip/hip_bf16.h>

#define B 16
#define S 4096
#define D 256
#define U 256
#define ROWS 32
#define NCHK 128         // chunks per batch
#define CPB 4            // chunks per block (DMA-pipelined)

typedef short short8 __attribute__((ext_vector_type(8)));
typedef float f32x4 __attribute__((ext_vector_type(4)));

__device__ __forceinline__ ushort f2bf(float f) {
    union { float f; uint u; } x{f};
    uint r = (x.u + 0x7fffu + ((x.u >> 16) & 1u)) >> 16;  // RNE
    return (ushort)r;
}

__device__ __forceinline__ float fast_tanh(float x) {
    float e = __expf(2.0f * x);
    return 1.0f - 2.0f * __builtin_amdgcn_rcpf(e + 1.0f);
}

// KA: setup. blocks 0..15: pqb GEMV (ILP-parallel); blocks 16..23: W1 pack.
__global__ void ka_setup(const float* __restrict__ query, const float* __restrict__ W2,
                         const float* __restrict__ b2, const float* __restrict__ b1,
                         const float* __restrict__ W1, float* __restrict__ pqb,
                         ushort* __restrict__ W1p) {
    __shared__ float pp[4][U];
    int bid = blockIdx.x, t = threadIdx.x;
    if (bid < 16) {
        const float* qb = query + bid * D;
        int u0 = (t & 63) * 4, dc = t >> 6;
        float4 a = {0.f, 0.f, 0.f, 0.f};
#pragma unroll 16
        for (int i = 0; i < 64; ++i) {
            int d = dc * 64 + i;
            float qd = qb[d];
            float4 wv = *(const float4*)&W2[d * U + u0];
            a.x = fmaf(qd, wv.x, a.x);
            a.y = fmaf(qd, wv.y, a.y);
            a.z = fmaf(qd, wv.z, a.z);
            a.w = fmaf(qd, wv.w, a.w);
        }
        *(float4*)&pp[dc][u0] = a;
        __syncthreads();
        pqb[bid * U + t] = pp[0][t] + pp[1][t] + pp[2][t] + pp[3][t] + b2[t] + b1[t];
    } else {
        int kk = bid - 16;
        int l = t & 63, g = t >> 6;
        int colu0 = l & 15;
        int k0 = kk * 32 + (l >> 4) * 8;
#pragma unroll
        for (int i = 0; i < 4; ++i) {
            int nt = g * 4 + i;
            int colu = nt * 16 + colu0;
            ushort* dst = W1p + (((nt * 8) + kk) * 64 + l) * 8;
#pragma unroll
            for (int e = 0; e < 8; ++e) dst[e] = f2bf(W1[(k0 + e) * U + colu]);
        }
    }
}

// KB: 512 blocks x CPB=4 chunks of 32 rows. Async global_load_lds DMA (fp32,
// src-pre-swizzled) overlaps the whole compute of the previous chunk; each
// wave converts its own 8 DMA'd rows to the r13-identical bf16 XOR layout.
__global__ __launch_bounds__(256, 2) void kb_scores(
    const float* __restrict__ values, const ushort* __restrict__ W1p,
    const float* __restrict__ pqb, const float* __restrict__ V,
    const float* __restrict__ bV, float* __restrict__ scores,
    float* __restrict__ cstats, float* __restrict__ cpart) {
    __shared__ float f32t[ROWS * 256];       // 32 KB, src-swizzled via DMA
    __shared__ ushort bft[2][ROWS * 256];    // 2 x 16 KB, XOR-swizzled bf16
    __shared__ float red[4][ROWS];
    __shared__ float wch[ROWS];
    const int t = threadIdx.x;
    const int w = t >> 6, l = t & 63;
    const int lrow = l & 15, lk = l >> 4;
    const int chunk0 = blockIdx.x * CPB;
    const int b = chunk0 >> 7;  // CPB chunks never straddle a batch

    float bb[4], vv[4];
#pragma unroll
    for (int nt = 0; nt < 4; ++nt) {
        int u = (w * 4 + nt) * 16 + lrow;
        bb[nt] = pqb[b * U + u];
        vv[nt] = V[u];
    }
    const float bV0 = bV[0];

    // DMA one chunk: wave w stages rows [w*8, w*8+8); lane l fetches the
    // (l ^ (r&7))-th 16B granule so the linear LDS write lands XOR-swizzled.
#define DMA_CHUNK(chunk)                                                          \
    {                                                                             \
        const float* vb = values + ((size_t)(b * S + ((chunk) & 127) * ROWS)) * D;\
        _Pragma("unroll")                                                         \
        for (int i = 0; i < 8; ++i) {                                             \
            int r = w * 8 + i;                                                    \
            const float* g = vb + r * 256 + ((l ^ (r & 7)) * 4);                  \
            __builtin_amdgcn_global_load_lds(                                     \
                (const __attribute__((address_space(1))) void*)g,                 \
                (__attribute__((address_space(3))) void*)&f32t[r * 256],          \
                16, 0, 0);                                                        \
        }                                                                         \
    }

    // Convert own-wave rows fp32 LDS -> bf16 LDS (r13-identical layout).
#define CONVERT_CHUNK(pb)                                                         \
    {                                                                             \
        _Pragma("unroll")                                                         \
        for (int i = 0; i < 8; ++i) {                                             \
            int r = w * 8 + i;                                                    \
            float4 v = *(const float4*)((const char*)f32t + r * 1024 +            \
                                        ((l * 16) ^ ((r & 7) << 4)));             \
            ushort4 h;                                                            \
            h.x = f2bf(v.x); h.y = f2bf(v.y); h.z = f2bf(v.z); h.w = f2bf(v.w);   \
            *(ushort4*)((char*)bft[pb] + r * 512 + ((l * 8) ^ ((r & 7) << 4))) = h;\
        }                                                                         \
    }

    DMA_CHUNK(chunk0);
    asm volatile("s_waitcnt vmcnt(0)" ::: "memory");
    __builtin_amdgcn_sched_barrier(0);
    CONVERT_CHUNK(0);

    for (int c = 0; c < CPB; ++c) {
        const int chunk = chunk0 + c;
        const int s0 = (chunk & 127) * ROWS;
        const char* bfb = (const char*)bft[c & 1];
        __syncthreads();  // publish bft[c&1]; f32t free for next DMA

        if (c + 1 < CPB) DMA_CHUNK(chunk + 1);  // flies under this chunk's compute

        // ---- MFMA scores ----
        f32x4 acc[2][4];
#pragma unroll
        for (int mt = 0; mt < 2; ++mt)
#pragma unroll
            for (int nt = 0; nt < 4; ++nt) acc[mt][nt] = (f32x4){0.f, 0.f, 0.f, 0.f};

#pragma unroll
        for (int kk = 0; kk < 8; ++kk) {
            short8 afr[2], bfr[4];
#pragma unroll
            for (int nt = 0; nt < 4; ++nt)
                bfr[nt] = *(const short8*)&W1p[((((w * 4 + nt) * 8) + kk) * 64 + l) * 8];
#pragma unroll
            for (int mt = 0; mt < 2; ++mt) {
                int row = mt * 16 + lrow;
                int byte = row * 512 + ((kk * 64 + lk * 16) ^ ((row & 7) << 4));
                afr[mt] = *(const short8*)(bfb + byte);
            }
#pragma unroll
            for (int mt = 0; mt < 2; ++mt)
#pragma unroll
                for (int nt = 0; nt < 4; ++nt)
                    acc[mt][nt] = __builtin_amdgcn_mfma_f32_16x16x32_bf16(
                        afr[mt], bfr[nt], acc[mt][nt], 0, 0, 0);
        }

        // ---- epilogue: tanh, .V, reduce over u ----
#pragma unroll
        for (int mt = 0; mt < 2; ++mt) {
#pragma unroll
            for (int r = 0; r < 4; ++r) {
                float s = 0.f;
#pragma unroll
                for (int nt = 0; nt < 4; ++nt)
                    s += fast_tanh(acc[mt][nt][r] + bb[nt]) * vv[nt];
                s += __shfl_xor(s, 1);
                s += __shfl_xor(s, 2);
                s += __shfl_xor(s, 4);
                s += __shfl_xor(s, 8);
                if (lrow == 0) red[w][mt * 16 + lk * 4 + r] = s;
            }
        }
        __syncthreads();

        if (t < ROWS) {  // lanes 0..31 of wave 0: scores + chunk stats
            float s = red[0][t] + red[1][t] + red[2][t] + red[3][t] + bV0;
            scores[b * S + s0 + t] = s;
            float m = s;
#pragma unroll
            for (int off = 16; off; off >>= 1) m = fmaxf(m, __shfl_xor(m, off));
            float z0 = __expf(s - m);
            wch[t] = z0;
            float z = z0;
#pragma unroll
            for (int off = 16; off; off >>= 1) z += __shfl_xor(z, off);
            if (t == 0) {
                cstats[2 * chunk] = m;
                cstats[2 * chunk + 1] = z;
            }
        }
        __syncthreads();

        // ---- partial context from bf16 LDS: thread t owns column t ----
        union { uint i; float f; } cv;
        float cacc = 0.f;
#pragma unroll 8
        for (int r = 0; r < ROWS; ++r) {
            int byte = r * 512 + ((t * 2) ^ ((r & 7) << 4));
            ushort u = *(const ushort*)(bfb + byte);
            cv.i = (uint)u << 16;
            cacc = fmaf(wch[r], cv.f, cacc);
        }
        cpart[(size_t)chunk * D + t] = cacc;

        // convert next chunk (own-wave rows; DMA had all of compute to land)
        if (c + 1 < CPB) {
            asm volatile("s_waitcnt vmcnt(0)" ::: "memory");
            __builtin_amdgcn_sched_barrier(0);
            CONVERT_CHUNK((c + 1) & 1);
        }
        // loop-top __syncthreads publishes bft[(c+1)&1]
    }
#undef DMA_CHUNK
#undef CONVERT_CHUNK
}

// KC: finisher, block = (batch b, quarter q); 128 chunks/batch.
__global__ void kc_final(const float* __restrict__ scores, const float* __restrict__ cstats,
                         const float* __restrict__ cpart, float* __restrict__ wout,
                         float* __restrict__ ctx) {
    __shared__ float scl[NCHK];
    __shared__ float stats2[2];
    __shared__ float part[4][64];
    int b = blockIdx.x >> 2, q = blockIdx.x & 3;
    int t = threadIdx.x;

    if (t < 64) {  // reduce 128 chunk stats with 64 lanes (2 each)
        float m1 = cstats[2 * (b * NCHK + t)];
        float z1 = cstats[2 * (b * NCHK + t) + 1];
        float m2 = cstats[2 * (b * NCHK + 64 + t)];
        float z2 = cstats[2 * (b * NCHK + 64 + t) + 1];
        float M = fmaxf(m1, m2);
#pragma unroll
        for (int off = 32; off; off >>= 1) M = fmaxf(M, __shfl_xor(M, off));
        float zz = z1 * __expf(m1 - M) + z2 * __expf(m2 - M);
#pragma unroll
        for (int off = 32; off; off >>= 1) zz += __shfl_xor(zz, off);
        if (t == 0) { stats2[0] = M; stats2[1] = zz; }
    }
    __syncthreads();
    float M = stats2[0];
    float invZ = 1.0f / stats2[1];
    if (t < NCHK) scl[t] = __expf(cstats[2 * (b * NCHK + t)] - M);
    __syncthreads();

    int tq = t >> 6, dl = t & 63;
    int d = q * 64 + dl;
    float acc = 0.f;
#pragma unroll
    for (int i = 0; i < 32; ++i) {
        int c = tq * 32 + i;
        acc = fmaf(scl[c], cpart[(size_t)(b * NCHK + c) * D + d], acc);
    }
    part[tq][dl] = acc;

#pragma unroll
    for (int i = 0; i < 4; ++i) {
        int ss = q * 1024 + i * 256 + t;
        wout[b * S + ss] = __expf(scores[b * S + ss] - M) * invZ;
    }
    __syncthreads();
    if (t < 64)
        ctx[b * D + q * 64 + t] =
            (part[0][t] + part[1][t] + part[2][t] + part[3][t]) * invZ;
}

extern "C" void kernel_launch(void* const* d_in, const int* in_sizes, int n_in,
                              void* d_out, int out_size, void* d_ws, size_t ws_size,
                              hipStream_t stream) {
    const float* values = (const float*)d_in[0];
    const float* query  = (const float*)d_in[1];
    const float* W1     = (const float*)d_in[2];
    const float* b1     = (const float*)d_in[3];
    const float* W2     = (const float*)d_in[4];
    const float* b2     = (const float*)d_in[5];
    const float* V      = (const float*)d_in[6];
    const float* bV     = (const float*)d_in[7];

    float* out  = (float*)d_out;
    float* ctx  = out;          // [B, D]
    float* wout = out + B * D;  // [B, S, 1]

    float* ws     = (float*)d_ws;
    float* pqb    = ws;                        // 4096
    float* scores = pqb + B * U;               // B*S = 65536
    float* cstats = scores + B * S;            // 2*B*NCHK = 4096
    float* cpart  = cstats + 2 * B * NCHK;     // B*NCHK*D = 524288
    ushort* W1p   = (ushort*)(cpart + (size_t)B * NCHK * D);  // 65536 ushorts

    ka_setup<<<24, 256, 0, stream>>>(query, W2, b2, b1, W1, pqb, W1p);
    kb_scores<<<B * NCHK / CPB, 256, 0, stream>>>(values, W1p, pqb, V, bV,
                                                  scores, cstats, cpart);
    kc_final<<<B * 4, 256, 0, stream>>>(scores, cstats, cpart, wout, ctx);
}

// Round 17
// 46.850 us; speedup vs baseline: 1.8361x; 1.1792x over previous
//
#include <hip/hip_runtime.h>
#include <hip/hip_bf16.h>

#define B 16
#define S 4096
#define D 256
#define U 256
#define ROWS 64
#define NCHK (S / ROWS)  // 64 chunks per batch

typedef short short8 __attribute__((ext_vector_type(8)));
typedef float f32x4 __attribute__((ext_vector_type(4)));

__device__ __forceinline__ ushort f2bf(float f) {
    union { float f; uint u; } x{f};
    uint r = (x.u + 0x7fffu + ((x.u >> 16) & 1u)) >> 16;  // RNE
    return (ushort)r;
}

__device__ __forceinline__ float fast_tanh(float x) {
    float e = __expf(2.0f * x);
    return 1.0f - 2.0f * __builtin_amdgcn_rcpf(e + 1.0f);
}

// KA: setup. blocks 0..15: pqb GEMV (ILP-parallel, r8-verified);
//            blocks 16..23: W1 pack into bf16 MFMA B-fragment order.
__global__ void ka_setup(const float* __restrict__ query, const float* __restrict__ W2,
                         const float* __restrict__ b2, const float* __restrict__ b1,
                         const float* __restrict__ W1, float* __restrict__ pqb,
                         ushort* __restrict__ W1p) {
    __shared__ float pp[4][U];
    int bid = blockIdx.x, t = threadIdx.x;
    if (bid < 16) {
        const float* qb = query + bid * D;
        int u0 = (t & 63) * 4, dc = t >> 6;
        float4 a = {0.f, 0.f, 0.f, 0.f};
#pragma unroll 16
        for (int i = 0; i < 64; ++i) {
            int d = dc * 64 + i;
            float qd = qb[d];
            float4 wv = *(const float4*)&W2[d * U + u0];
            a.x = fmaf(qd, wv.x, a.x);
            a.y = fmaf(qd, wv.y, a.y);
            a.z = fmaf(qd, wv.z, a.z);
            a.w = fmaf(qd, wv.w, a.w);
        }
        *(float4*)&pp[dc][u0] = a;
        __syncthreads();
        pqb[bid * U + t] = pp[0][t] + pp[1][t] + pp[2][t] + pp[3][t] + b2[t] + b1[t];
    } else {
        int kk = bid - 16;
        int l = t & 63, g = t >> 6;
        int colu0 = l & 15;
        int k0 = kk * 32 + (l >> 4) * 8;
#pragma unroll
        for (int i = 0; i < 4; ++i) {
            int nt = g * 4 + i;
            int colu = nt * 16 + colu0;
            ushort* dst = W1p + (((nt * 8) + kk) * 64 + l) * 8;
#pragma unroll
            for (int e = 0; e < 8; ++e) dst[e] = f2bf(W1[(k0 + e) * U + colu]);
        }
    }
}

// KB: per 64-row chunk (r13-verbatim core): staged-LDS bf16 MFMA scores,
// chunk softmax stats, unnormalized weights z0 -> wout (KC rescales in place),
// bf16-LDS partial context -> cpart. No fences/atomics.
__global__ __launch_bounds__(256, 4) void kb_scores(
    const float* __restrict__ values, const ushort* __restrict__ W1p,
    const float* __restrict__ pqb, const float* __restrict__ V,
    const float* __restrict__ bV, float* __restrict__ cstats,
    float* __restrict__ cpart, float* __restrict__ wout) {
    __shared__ ushort Alds[ROWS * 256];  // 32 KB, XOR-swizzled bf16 tile
    __shared__ float red[4][ROWS];
    __shared__ float wch[ROWS];
    int b = blockIdx.x >> 6;
    int s0 = (blockIdx.x & 63) * ROWS;
    int t = threadIdx.x;
    int w = t >> 6, l = t & 63;
    char* lds = (char*)Alds;

    // stage 64x256 fp32 -> bf16 LDS, byte ^= (row&7)<<4 (issue-all-then-convert)
    const float* src = values + ((size_t)(b * S + s0)) * D;
    float4 vreg[16];
#pragma unroll
    for (int i = 0; i < 16; ++i)
        vreg[i] = *(const float4*)&src[(i * 4 + w) * 256 + l * 4];
#pragma unroll
    for (int i = 0; i < 16; ++i) {
        int row = i * 4 + w;
        int col = l * 4;
        ushort4 h;
        h.x = f2bf(vreg[i].x); h.y = f2bf(vreg[i].y);
        h.z = f2bf(vreg[i].z); h.w = f2bf(vreg[i].w);
        int byte = (row * 512 + col * 2) ^ ((row & 7) << 4);
        *(ushort4*)(lds + byte) = h;
    }
    __syncthreads();

    // MFMA scores (kk fully unrolled)
    int lrow = l & 15, lk = l >> 4;
    f32x4 acc[4][4];
#pragma unroll
    for (int mt = 0; mt < 4; ++mt)
#pragma unroll
        for (int nt = 0; nt < 4; ++nt) acc[mt][nt] = (f32x4){0.f, 0.f, 0.f, 0.f};

#pragma unroll
    for (int kk = 0; kk < 8; ++kk) {
        short8 afr[4], bfr[4];
#pragma unroll
        for (int nt = 0; nt < 4; ++nt) {
            int ntile = w * 4 + nt;
            bfr[nt] = *(const short8*)&W1p[(((ntile * 8) + kk) * 64 + l) * 8];
        }
#pragma unroll
        for (int mt = 0; mt < 4; ++mt) {
            int row = mt * 16 + lrow;
            int byte = (row * 512 + kk * 64 + lk * 16) ^ ((row & 7) << 4);
            afr[mt] = *(const short8*)(lds + byte);
        }
#pragma unroll
        for (int mt = 0; mt < 4; ++mt)
#pragma unroll
            for (int nt = 0; nt < 4; ++nt)
                acc[mt][nt] = __builtin_amdgcn_mfma_f32_16x16x32_bf16(
                    afr[mt], bfr[nt], acc[mt][nt], 0, 0, 0);
    }

    // epilogue: tanh, .V, reduce over u
    float bb[4], vv[4];
#pragma unroll
    for (int nt = 0; nt < 4; ++nt) {
        int u = (w * 4 + nt) * 16 + lrow;
        bb[nt] = pqb[b * U + u];
        vv[nt] = V[u];
    }
#pragma unroll
    for (int mt = 0; mt < 4; ++mt) {
#pragma unroll
        for (int r = 0; r < 4; ++r) {
            float s = 0.f;
#pragma unroll
            for (int nt = 0; nt < 4; ++nt)
                s += fast_tanh(acc[mt][nt][r] + bb[nt]) * vv[nt];
            s += __shfl_xor(s, 1);
            s += __shfl_xor(s, 2);
            s += __shfl_xor(s, 4);
            s += __shfl_xor(s, 8);
            if (lrow == 0) red[w][mt * 16 + lk * 4 + r] = s;
        }
    }
    __syncthreads();

    if (t < ROWS) {  // wave 0: chunk stats + unnormalized weights -> wout
        float s = red[0][t] + red[1][t] + red[2][t] + red[3][t] + bV[0];
        float m = s;
#pragma unroll
        for (int off = 32; off; off >>= 1) m = fmaxf(m, __shfl_xor(m, off));
        float z0 = __expf(s - m);
        wch[t] = z0;
        wout[b * S + s0 + t] = z0;  // KC rescales in place
        float z = z0;
#pragma unroll
        for (int off = 32; off; off >>= 1) z += __shfl_xor(z, off);
        if (t == 0) {
            cstats[2 * blockIdx.x] = m;
            cstats[2 * blockIdx.x + 1] = z;
        }
    }
    __syncthreads();

    // partial context from the bf16 LDS copy: thread t owns column t
    union { uint i; float f; } cv;
    float cacc = 0.f;
#pragma unroll 8
    for (int r = 0; r < ROWS; ++r) {
        int byte = (r * 512 + t * 2) ^ ((r & 7) << 4);
        ushort u = *(const ushort*)(lds + byte);
        cv.i = (uint)u << 16;
        cacc = fmaf(wch[r], cv.f, cacc);
    }
    cpart[(size_t)blockIdx.x * D + t] = cacc;
}

// KC: finisher, block = (batch b, quarter q); in-place wout rescale (r9-verified).
__global__ void kc_final(const float* __restrict__ cstats, const float* __restrict__ cpart,
                         float* __restrict__ wout, float* __restrict__ ctx) {
    __shared__ float scl[NCHK];
    __shared__ float stats2[2];
    __shared__ float part[4][64];
    int b = blockIdx.x >> 2, q = blockIdx.x & 3;
    int t = threadIdx.x;

    if (t < NCHK) {
        float m = cstats[2 * (b * NCHK + t)];
        float z = cstats[2 * (b * NCHK + t) + 1];
        float M = m;
#pragma unroll
        for (int off = 32; off; off >>= 1) M = fmaxf(M, __shfl_xor(M, off));
        float zz = z * __expf(m - M);
#pragma unroll
        for (int off = 32; off; off >>= 1) zz += __shfl_xor(zz, off);
        scl[t] = __expf(m - M);
        if (t == 0) { stats2[0] = M; stats2[1] = zz; }
    }
    __syncthreads();
    float invZ = 1.0f / stats2[1];

    int tq = t >> 6, dl = t & 63;
    int d = q * 64 + dl;
    float acc = 0.f;
#pragma unroll
    for (int i = 0; i < 16; ++i) {
        int c = tq * 16 + i;
        acc = fmaf(scl[c], cpart[(size_t)(b * NCHK + c) * D + d], acc);
    }
    part[tq][dl] = acc;

#pragma unroll
    for (int i = 0; i < 4; ++i) {
        int ss = q * 1024 + i * 256 + t;
        wout[b * S + ss] *= scl[ss >> 6] * invZ;
    }
    __syncthreads();
    if (t < 64)
        ctx[b * D + q * 64 + t] =
            (part[0][t] + part[1][t] + part[2][t] + part[3][t]) * invZ;
}

extern "C" void kernel_launch(void* const* d_in, const int* in_sizes, int n_in,
                              void* d_out, int out_size, void* d_ws, size_t ws_size,
                              hipStream_t stream) {
    const float* values = (const float*)d_in[0];
    const float* query  = (const float*)d_in[1];
    const float* W1     = (const float*)d_in[2];
    const float* b1     = (const float*)d_in[3];
    const float* W2     = (const float*)d_in[4];
    const float* b2     = (const float*)d_in[5];
    const float* V      = (const float*)d_in[6];
    const float* bV     = (const float*)d_in[7];

    float* out  = (float*)d_out;
    float* ctx  = out;          // [B, D]
    float* wout = out + B * D;  // [B, S, 1]

    float* ws     = (float*)d_ws;
    float* pqb    = ws;                 // 4096
    float* cstats = pqb + B * U;        // 2*B*NCHK = 2048
    float* cpart  = cstats + 2048;      // B*NCHK*D = 262144
    ushort* W1p   = (ushort*)(cpart + (size_t)B * NCHK * D);  // 65536 ushorts

    ka_setup<<<24, 256, 0, stream>>>(query, W2, b2, b1, W1, pqb, W1p);
    kb_scores<<<B * NCHK, 256, 0, stream>>>(values, W1p, pqb, V, bV,
                                            cstats, cpart, wout);
    kc_final<<<B * 4, 256, 0, stream>>>(cstats, cpart, wout, ctx);
}

// Round 18
// 44.104 us; speedup vs baseline: 1.9504x; 1.0623x over previous
//
#include <hip/hip_runtime.h>
#include <hip/hip_bf16.h>

#define B 16
#define S 4096
#define D 256
#define U 256
#define ROWS 64    // rows per block in score kernel
#define NCHK (S / ROWS)  // 64 chunks per batch

typedef short short8 __attribute__((ext_vector_type(8)));
typedef float f32x4 __attribute__((ext_vector_type(4)));

__device__ __forceinline__ ushort f2bf(float f) {
    union { float f; uint u; } x{f};
    uint r = (x.u + 0x7fffu + ((x.u >> 16) & 1u)) >> 16;  // RNE
    return (ushort)r;
}

__device__ __forceinline__ float fast_tanh(float x) {
    // tanh(x) = 1 - 2/(e^2x + 1);  e^2x = exp2(x * 2*log2(e))
    float e = exp2f(x * 2.885390081777927f);
    return 1.0f - 2.0f * __builtin_amdgcn_rcpf(e + 1.0f);
}

// KA: fused setup (r13 verbatim).
__global__ void ka_setup(const float* __restrict__ q, const float* __restrict__ W2,
                         const float* __restrict__ b2, const float* __restrict__ b1,
                         const float* __restrict__ W1, float* __restrict__ pqb,
                         ushort* __restrict__ W1p) {
    int bid = blockIdx.x, t = threadIdx.x;
    if (bid < 16) {
        int b = bid, u = t;
        const float* qb = q + b * D;
        float acc = b2[u] + b1[u];
#pragma unroll 8
        for (int d = 0; d < D; ++d)
            acc = fmaf(qb[d], W2[d * U + u], acc);
        pqb[b * U + u] = acc;
    } else {
        int kk = bid - 16;
        int l = t & 63, g = t >> 6;
        int colu0 = l & 15;
        int k0 = kk * 32 + (l >> 4) * 8;
#pragma unroll
        for (int i = 0; i < 4; ++i) {
            int nt = g * 4 + i;
            int colu = nt * 16 + colu0;
            ushort* dst = W1p + (((nt * 8) + kk) * 64 + l) * 8;
#pragma unroll
            for (int e = 0; e < 8; ++e) dst[e] = f2bf(W1[(k0 + e) * U + colu]);
        }
    }
}

// KB: r13 core + {bb-in-acc-init, exp2 tanh, cpart dual-acc, XCD swizzle}.
__global__ __launch_bounds__(256, 4) void kb_scores(
    const float* __restrict__ values, const ushort* __restrict__ W1p,
    const float* __restrict__ pqb, const float* __restrict__ V,
    const float* __restrict__ bV, float* __restrict__ scores,
    float* __restrict__ cstats, float* __restrict__ cpart) {
    __shared__ ushort Alds[ROWS * 256];  // 32 KB, XOR-swizzled bf16 tile
    __shared__ float red[4][ROWS];
    __shared__ float wch[ROWS];
    // T1: bijective XCD swizzle (1024 blocks = 8 XCD x 128 contiguous chunks)
    const int chunk = (blockIdx.x & 7) * 128 + (blockIdx.x >> 3);
    int b = chunk >> 6;
    int s0 = (chunk & 63) * ROWS;
    int t = threadIdx.x;
    int w = t >> 6, l = t & 63;
    char* lds = (char*)Alds;

    // stage 64x256 fp32 -> bf16 LDS, byte ^= (row&7)<<4 (issue-all-then-convert)
    const float* src = values + ((size_t)(b * S + s0)) * D;
    float4 vreg[16];
#pragma unroll
    for (int i = 0; i < 16; ++i)
        vreg[i] = *(const float4*)&src[(i * 4 + w) * 256 + l * 4];
#pragma unroll
    for (int i = 0; i < 16; ++i) {
        int row = i * 4 + w;
        int col = l * 4;
        ushort4 h;
        h.x = f2bf(vreg[i].x); h.y = f2bf(vreg[i].y);
        h.z = f2bf(vreg[i].z); h.w = f2bf(vreg[i].w);
        int byte = (row * 512 + col * 2) ^ ((row & 7) << 4);
        *(ushort4*)(lds + byte) = h;
    }
    __syncthreads();

    // MFMA scores (kk fully unrolled); acc starts at bb[nt] (epilogue add folded)
    int lrow = l & 15, lk = l >> 4;
    float bb[4], vv[4];
#pragma unroll
    for (int nt = 0; nt < 4; ++nt) {
        int u = (w * 4 + nt) * 16 + lrow;
        bb[nt] = pqb[b * U + u];
        vv[nt] = V[u];
    }
    f32x4 acc[4][4];
#pragma unroll
    for (int mt = 0; mt < 4; ++mt)
#pragma unroll
        for (int nt = 0; nt < 4; ++nt)
            acc[mt][nt] = (f32x4){bb[nt], bb[nt], bb[nt], bb[nt]};

#pragma unroll
    for (int kk = 0; kk < 8; ++kk) {
        short8 afr[4], bfr[4];
#pragma unroll
        for (int nt = 0; nt < 4; ++nt) {
            int ntile = w * 4 + nt;
            bfr[nt] = *(const short8*)&W1p[(((ntile * 8) + kk) * 64 + l) * 8];
        }
#pragma unroll
        for (int mt = 0; mt < 4; ++mt) {
            int row = mt * 16 + lrow;
            int byte = (row * 512 + kk * 64 + lk * 16) ^ ((row & 7) << 4);
            afr[mt] = *(const short8*)(lds + byte);
        }
#pragma unroll
        for (int mt = 0; mt < 4; ++mt)
#pragma unroll
            for (int nt = 0; nt < 4; ++nt)
                acc[mt][nt] = __builtin_amdgcn_mfma_f32_16x16x32_bf16(
                    afr[mt], bfr[nt], acc[mt][nt], 0, 0, 0);
    }

    // epilogue: tanh, .V, reduce over u
#pragma unroll
    for (int mt = 0; mt < 4; ++mt) {
#pragma unroll
        for (int r = 0; r < 4; ++r) {
            float s = 0.f;
#pragma unroll
            for (int nt = 0; nt < 4; ++nt)
                s += fast_tanh(acc[mt][nt][r]) * vv[nt];
            s += __shfl_xor(s, 1);
            s += __shfl_xor(s, 2);
            s += __shfl_xor(s, 4);
            s += __shfl_xor(s, 8);
            if (lrow == 0) red[w][mt * 16 + lk * 4 + r] = s;
        }
    }
    __syncthreads();
    if (t < ROWS) {  // wave 0
        float s = red[0][t] + red[1][t] + red[2][t] + red[3][t] + bV[0];
        scores[b * S + s0 + t] = s;
        float m = s;
#pragma unroll
        for (int off = 32; off; off >>= 1) m = fmaxf(m, __shfl_xor(m, off));
        float z0 = __expf(s - m);
        wch[t] = z0;
        float z = z0;
#pragma unroll
        for (int off = 32; off; off >>= 1) z += __shfl_xor(z, off);
        if (t == 0) {
            cstats[2 * chunk] = m;
            cstats[2 * chunk + 1] = z;
        }
    }
    __syncthreads();

    // partial context from the bf16 LDS copy: thread t owns column t (dual acc)
    union { uint i; float f; } cv0, cv1;
    float c0 = 0.f, c1 = 0.f;
#pragma unroll 8
    for (int r = 0; r < ROWS; r += 2) {
        int byte0 = (r * 512 + t * 2) ^ ((r & 7) << 4);
        int byte1 = ((r + 1) * 512 + t * 2) ^ (((r + 1) & 7) << 4);
        ushort u0 = *(const ushort*)(lds + byte0);
        ushort u1 = *(const ushort*)(lds + byte1);
        cv0.i = (uint)u0 << 16;
        cv1.i = (uint)u1 << 16;
        c0 = fmaf(wch[r], cv0.f, c0);
        c1 = fmaf(wch[r + 1], cv1.f, c1);
    }
    cpart[(size_t)chunk * D + t] = c0 + c1;
}

// KC: finisher. 4 blocks per batch (q = quarter). (r13 verbatim)
__global__ void kc_final(const float* __restrict__ scores, const float* __restrict__ cstats,
                         const float* __restrict__ cpart, float* __restrict__ wout,
                         float* __restrict__ ctx) {
    __shared__ float scl[NCHK];
    __shared__ float stats[2];
    __shared__ float part[4][64];
    int b = blockIdx.x >> 2, q = blockIdx.x & 3;
    int t = threadIdx.x;

    if (t < 64) {
        float m = cstats[2 * (b * NCHK + t)];
        float z = cstats[2 * (b * NCHK + t) + 1];
        float M = m;
#pragma unroll
        for (int off = 32; off; off >>= 1) M = fmaxf(M, __shfl_xor(M, off));
        float zz = z * __expf(m - M);
#pragma unroll
        for (int off = 32; off; off >>= 1) zz += __shfl_xor(zz, off);
        scl[t] = __expf(m - M);
        if (t == 0) { stats[0] = M; stats[1] = zz; }
    }
    __syncthreads();
    float M = stats[0];
    float invZ = 1.0f / stats[1];

    int tq = t >> 6, dl = t & 63;
    int d = q * 64 + dl;
    float acc = 0.f;
#pragma unroll
    for (int i = 0; i < 16; ++i) {
        int c = tq * 16 + i;
        acc = fmaf(scl[c], cpart[(size_t)(b * NCHK + c) * D + d], acc);
    }
    part[tq][dl] = acc;

#pragma unroll
    for (int i = 0; i < 4; ++i) {
        int s = q * 1024 + i * 256 + t;
        wout[b * S + s] = __expf(scores[b * S + s] - M) * invZ;
    }
    __syncthreads();
    if (t < 64)
        ctx[b * D + q * 64 + t] =
            (part[0][t] + part[1][t] + part[2][t] + part[3][t]) * invZ;
}

extern "C" void kernel_launch(void* const* d_in, const int* in_sizes, int n_in,
                              void* d_out, int out_size, void* d_ws, size_t ws_size,
                              hipStream_t stream) {
    const float* values = (const float*)d_in[0];
    const float* query  = (const float*)d_in[1];
    const float* W1     = (const float*)d_in[2];
    const float* b1     = (const float*)d_in[3];
    const float* W2     = (const float*)d_in[4];
    const float* b2     = (const float*)d_in[5];
    const float* V      = (const float*)d_in[6];
    const float* bV     = (const float*)d_in[7];

    float* out  = (float*)d_out;
    float* ctx  = out;          // [B, D]
    float* wout = out + B * D;  // [B, S, 1]

    float* ws     = (float*)d_ws;
    float* pqb    = ws;                 // B*U          = 4096
    float* scores = pqb + B * U;        // B*S          = 65536
    float* cstats = scores + B * S;     // 2*B*NCHK     = 2048
    float* cpart  = cstats + 2048;      // B*NCHK*D     = 262144
    ushort* W1p   = (ushort*)(cpart + B * NCHK * D);  // 65536 ushorts

    ka_setup<<<24, 256, 0, stream>>>(query, W2, b2, b1, W1, pqb, W1p);
    kb_scores<<<B * NCHK, 256, 0, stream>>>(values, W1p, pqb, V, bV, scores, cstats, cpart);
    kc_final<<<B * 4, 256, 0, stream>>>(scores, cstats, cpart, wout, ctx);
}

// Round 19
// 44.059 us; speedup vs baseline: 1.9524x; 1.0010x over previous
//
#include <hip/hip_runtime.h>
#include <hip/hip_bf16.h>

#define B 16
#define S 4096
#define D 256
#define U 256
#define ROWS 64    // rows per block in score kernel
#define NCHK (S / ROWS)  // 64 chunks per batch

typedef short short8 __attribute__((ext_vector_type(8)));
typedef float f32x4 __attribute__((ext_vector_type(4)));

__device__ __forceinline__ ushort f2bf(float f) {
    union { float f; uint u; } x{f};
    uint r = (x.u + 0x7fffu + ((x.u >> 16) & 1u)) >> 16;  // RNE
    return (ushort)r;
}

__device__ __forceinline__ float fast_tanh(float x) {
    // tanh(x) = 1 - 2/(e^2x + 1);  e^2x = exp2(x * 2*log2(e))
    float e = exp2f(x * 2.885390081777927f);
    return 1.0f - 2.0f * __builtin_amdgcn_rcpf(e + 1.0f);
}

// KA: fused setup (r13 verbatim).
__global__ void ka_setup(const float* __restrict__ q, const float* __restrict__ W2,
                         const float* __restrict__ b2, const float* __restrict__ b1,
                         const float* __restrict__ W1, float* __restrict__ pqb,
                         ushort* __restrict__ W1p) {
    int bid = blockIdx.x, t = threadIdx.x;
    if (bid < 16) {
        int b = bid, u = t;
        const float* qb = q + b * D;
        float acc = b2[u] + b1[u];
#pragma unroll 8
        for (int d = 0; d < D; ++d)
            acc = fmaf(qb[d], W2[d * U + u], acc);
        pqb[b * U + u] = acc;
    } else {
        int kk = bid - 16;
        int l = t & 63, g = t >> 6;
        int colu0 = l & 15;
        int k0 = kk * 32 + (l >> 4) * 8;
#pragma unroll
        for (int i = 0; i < 4; ++i) {
            int nt = g * 4 + i;
            int colu = nt * 16 + colu0;
            ushort* dst = W1p + (((nt * 8) + kk) * 64 + l) * 8;
#pragma unroll
            for (int e = 0; e < 8; ++e) dst[e] = f2bf(W1[(k0 + e) * U + colu]);
        }
    }
}

// KB: r13 core + {bb-in-acc-init, exp2 tanh, cpart dual-acc}. No XCD swizzle.
__global__ __launch_bounds__(256, 4) void kb_scores(
    const float* __restrict__ values, const ushort* __restrict__ W1p,
    const float* __restrict__ pqb, const float* __restrict__ V,
    const float* __restrict__ bV, float* __restrict__ scores,
    float* __restrict__ cstats, float* __restrict__ cpart) {
    __shared__ ushort Alds[ROWS * 256];  // 32 KB, XOR-swizzled bf16 tile
    __shared__ float red[4][ROWS];
    __shared__ float wch[ROWS];
    int b = blockIdx.x >> 6;
    int s0 = (blockIdx.x & 63) * ROWS;
    int t = threadIdx.x;
    int w = t >> 6, l = t & 63;
    char* lds = (char*)Alds;

    // stage 64x256 fp32 -> bf16 LDS, byte ^= (row&7)<<4 (issue-all-then-convert)
    const float* src = values + ((size_t)(b * S + s0)) * D;
    float4 vreg[16];
#pragma unroll
    for (int i = 0; i < 16; ++i)
        vreg[i] = *(const float4*)&src[(i * 4 + w) * 256 + l * 4];
#pragma unroll
    for (int i = 0; i < 16; ++i) {
        int row = i * 4 + w;
        int col = l * 4;
        ushort4 h;
        h.x = f2bf(vreg[i].x); h.y = f2bf(vreg[i].y);
        h.z = f2bf(vreg[i].z); h.w = f2bf(vreg[i].w);
        int byte = (row * 512 + col * 2) ^ ((row & 7) << 4);
        *(ushort4*)(lds + byte) = h;
    }
    __syncthreads();

    // MFMA scores (kk fully unrolled); acc starts at bb[nt] (epilogue add folded)
    int lrow = l & 15, lk = l >> 4;
    float bb[4], vv[4];
#pragma unroll
    for (int nt = 0; nt < 4; ++nt) {
        int u = (w * 4 + nt) * 16 + lrow;
        bb[nt] = pqb[b * U + u];
        vv[nt] = V[u];
    }
    f32x4 acc[4][4];
#pragma unroll
    for (int mt = 0; mt < 4; ++mt)
#pragma unroll
        for (int nt = 0; nt < 4; ++nt)
            acc[mt][nt] = (f32x4){bb[nt], bb[nt], bb[nt], bb[nt]};

#pragma unroll
    for (int kk = 0; kk < 8; ++kk) {
        short8 afr[4], bfr[4];
#pragma unroll
        for (int nt = 0; nt < 4; ++nt) {
            int ntile = w * 4 + nt;
            bfr[nt] = *(const short8*)&W1p[(((ntile * 8) + kk) * 64 + l) * 8];
        }
#pragma unroll
        for (int mt = 0; mt < 4; ++mt) {
            int row = mt * 16 + lrow;
            int byte = (row * 512 + kk * 64 + lk * 16) ^ ((row & 7) << 4);
            afr[mt] = *(const short8*)(lds + byte);
        }
#pragma unroll
        for (int mt = 0; mt < 4; ++mt)
#pragma unroll
            for (int nt = 0; nt < 4; ++nt)
                acc[mt][nt] = __builtin_amdgcn_mfma_f32_16x16x32_bf16(
                    afr[mt], bfr[nt], acc[mt][nt], 0, 0, 0);
    }

    // epilogue: tanh, .V, reduce over u
#pragma unroll
    for (int mt = 0; mt < 4; ++mt) {
#pragma unroll
        for (int r = 0; r < 4; ++r) {
            float s = 0.f;
#pragma unroll
            for (int nt = 0; nt < 4; ++nt)
                s += fast_tanh(acc[mt][nt][r]) * vv[nt];
            s += __shfl_xor(s, 1);
            s += __shfl_xor(s, 2);
            s += __shfl_xor(s, 4);
            s += __shfl_xor(s, 8);
            if (lrow == 0) red[w][mt * 16 + lk * 4 + r] = s;
        }
    }
    __syncthreads();
    if (t < ROWS) {  // wave 0
        float s = red[0][t] + red[1][t] + red[2][t] + red[3][t] + bV[0];
        scores[b * S + s0 + t] = s;
        float m = s;
#pragma unroll
        for (int off = 32; off; off >>= 1) m = fmaxf(m, __shfl_xor(m, off));
        float z0 = __expf(s - m);
        wch[t] = z0;
        float z = z0;
#pragma unroll
        for (int off = 32; off; off >>= 1) z += __shfl_xor(z, off);
        if (t == 0) {
            cstats[2 * blockIdx.x] = m;
            cstats[2 * blockIdx.x + 1] = z;
        }
    }
    __syncthreads();

    // partial context from the bf16 LDS copy: thread t owns column t (dual acc)
    union { uint i; float f; } cv0, cv1;
    float c0 = 0.f, c1 = 0.f;
#pragma unroll 8
    for (int r = 0; r < ROWS; r += 2) {
        int byte0 = (r * 512 + t * 2) ^ ((r & 7) << 4);
        int byte1 = ((r + 1) * 512 + t * 2) ^ (((r + 1) & 7) << 4);
        ushort u0 = *(const ushort*)(lds + byte0);
        ushort u1 = *(const ushort*)(lds + byte1);
        cv0.i = (uint)u0 << 16;
        cv1.i = (uint)u1 << 16;
        c0 = fmaf(wch[r], cv0.f, c0);
        c1 = fmaf(wch[r + 1], cv1.f, c1);
    }
    cpart[(size_t)blockIdx.x * D + t] = c0 + c1;
}

// KC: finisher. 4 blocks per batch (q = quarter). (r13 verbatim)
__global__ void kc_final(const float* __restrict__ scores, const float* __restrict__ cstats,
                         const float* __restrict__ cpart, float* __restrict__ wout,
                         float* __restrict__ ctx) {
    __shared__ float scl[NCHK];
    __shared__ float stats[2];
    __shared__ float part[4][64];
    int b = blockIdx.x >> 2, q = blockIdx.x & 3;
    int t = threadIdx.x;

    if (t < 64) {
        float m = cstats[2 * (b * NCHK + t)];
        float z = cstats[2 * (b * NCHK + t) + 1];
        float M = m;
#pragma unroll
        for (int off = 32; off; off >>= 1) M = fmaxf(M, __shfl_xor(M, off));
        float zz = z * __expf(m - M);
#pragma unroll
        for (int off = 32; off; off >>= 1) zz += __shfl_xor(zz, off);
        scl[t] = __expf(m - M);
        if (t == 0) { stats[0] = M; stats[1] = zz; }
    }
    __syncthreads();
    float M = stats[0];
    float invZ = 1.0f / stats[1];

    int tq = t >> 6, dl = t & 63;
    int d = q * 64 + dl;
    float acc = 0.f;
#pragma unroll
    for (int i = 0; i < 16; ++i) {
        int c = tq * 16 + i;
        acc = fmaf(scl[c], cpart[(size_t)(b * NCHK + c) * D + d], acc);
    }
    part[tq][dl] = acc;

#pragma unroll
    for (int i = 0; i < 4; ++i) {
        int s = q * 1024 + i * 256 + t;
        wout[b * S + s] = __expf(scores[b * S + s] - M) * invZ;
    }
    __syncthreads();
    if (t < 64)
        ctx[b * D + q * 64 + t] =
            (part[0][t] + part[1][t] + part[2][t] + part[3][t]) * invZ;
}

extern "C" void kernel_launch(void* const* d_in, const int* in_sizes, int n_in,
                              void* d_out, int out_size, void* d_ws, size_t ws_size,
                              hipStream_t stream) {
    const float* values = (const float*)d_in[0];
    const float* query  = (const float*)d_in[1];
    const float* W1     = (const float*)d_in[2];
    const float* b1     = (const float*)d_in[3];
    const float* W2     = (const float*)d_in[4];
    const float* b2     = (const float*)d_in[5];
    const float* V      = (const float*)d_in[6];
    const float* bV     = (const float*)d_in[7];

    float* out  = (float*)d_out;
    float* ctx  = out;          // [B, D]
    float* wout = out + B * D;  // [B, S, 1]

    float* ws     = (float*)d_ws;
    float* pqb    = ws;                 // B*U          = 4096
    float* scores = pqb + B * U;        // B*S          = 65536
    float* cstats = scores + B * S;     // 2*B*NCHK     = 2048
    float* cpart  = cstats + 2048;      // B*NCHK*D     = 262144
    ushort* W1p   = (ushort*)(cpart + B * NCHK * D);  // 65536 ushorts

    ka_setup<<<24, 256, 0, stream>>>(query, W2, b2, b1, W1, pqb, W1p);
    kb_scores<<<B * NCHK, 256, 0, stream>>>(values, W1p, pqb, V, bV, scores, cstats, cpart);
    kc_final<<<B * 4, 256, 0, stream>>>(scores, cstats, cpart, wout, ctx);
}

// Round 20
// 42.538 us; speedup vs baseline: 2.0222x; 1.0358x over previous
//
#include <hip/hip_runtime.h>
#include <hip/hip_bf16.h>

#define B 16
#define S 4096
#define D 256
#define U 256
#define ROWS 64    // rows per block in score kernel
#define NCHK (S / ROWS)  // 64 chunks per batch

typedef short short8 __attribute__((ext_vector_type(8)));
typedef float f32x4 __attribute__((ext_vector_type(4)));

__device__ __forceinline__ ushort f2bf(float f) {
    union { float f; uint u; } x{f};
    uint r = (x.u + 0x7fffu + ((x.u >> 16) & 1u)) >> 16;  // RNE
    return (ushort)r;
}

__device__ __forceinline__ float fast_tanh(float x) {
    float e = __expf(2.0f * x);
    return 1.0f - 2.0f * __builtin_amdgcn_rcpf(e + 1.0f);
}

// KA: fused setup.
//  blocks 0..15 : pqb[b][u] = query[b,:].W2[:,u] + b2[u] + b1[u]
//  blocks 16..23: pack W1 (fp32 [D][U]) into bf16 MFMA B-fragment order, one kk each
__global__ void ka_setup(const float* __restrict__ q, const float* __restrict__ W2,
                         const float* __restrict__ b2, const float* __restrict__ b1,
                         const float* __restrict__ W1, float* __restrict__ pqb,
                         ushort* __restrict__ W1p) {
    int bid = blockIdx.x, t = threadIdx.x;
    if (bid < 16) {
        int b = bid, u = t;
        const float* qb = q + b * D;
        float acc = b2[u] + b1[u];
#pragma unroll 8
        for (int d = 0; d < D; ++d)
            acc = fmaf(qb[d], W2[d * U + u], acc);
        pqb[b * U + u] = acc;
    } else {
        int kk = bid - 16;
        int l = t & 63, g = t >> 6;
        int colu0 = l & 15;
        int k0 = kk * 32 + (l >> 4) * 8;
#pragma unroll
        for (int i = 0; i < 4; ++i) {
            int nt = g * 4 + i;
            int colu = nt * 16 + colu0;
            ushort* dst = W1p + (((nt * 8) + kk) * 64 + l) * 8;
#pragma unroll
            for (int e = 0; e < 8; ++e) dst[e] = f2bf(W1[(k0 + e) * U + colu]);
        }
    }
}

// KB: per 64-row chunk: scores via bf16 MFMA, chunk softmax stats (m_c, z_c),
// and unnormalized partial context from the bf16 LDS copy (single HBM pass).
__global__ __launch_bounds__(256, 4) void kb_scores(
    const float* __restrict__ values, const ushort* __restrict__ W1p,
    const float* __restrict__ pqb, const float* __restrict__ V,
    const float* __restrict__ bV, float* __restrict__ scores,
    float* __restrict__ cstats, float* __restrict__ cpart) {
    __shared__ ushort Alds[ROWS * 256];  // 32 KB, XOR-swizzled bf16 tile
    __shared__ float red[4][ROWS];
    __shared__ float wch[ROWS];
    int b = blockIdx.x >> 6;
    int s0 = (blockIdx.x & 63) * ROWS;
    int t = threadIdx.x;
    int w = t >> 6, l = t & 63;
    char* lds = (char*)Alds;

    // ---- stage 64x256 fp32 -> bf16 LDS, byte ^= (row&7)<<4 ----
    // Phase 1: issue ALL 16 float4 loads (64 VGPRs) so they overlap in flight.
    const float* src = values + ((size_t)(b * S + s0)) * D;
    float4 vreg[16];
#pragma unroll
    for (int i = 0; i < 16; ++i)
        vreg[i] = *(const float4*)&src[(i * 4 + w) * 256 + l * 4];
    // Phase 2: convert + swizzled LDS write.
#pragma unroll
    for (int i = 0; i < 16; ++i) {
        int row = i * 4 + w;
        int col = l * 4;
        ushort4 h;
        h.x = f2bf(vreg[i].x); h.y = f2bf(vreg[i].y);
        h.z = f2bf(vreg[i].z); h.w = f2bf(vreg[i].w);
        int byte = (row * 512 + col * 2) ^ ((row & 7) << 4);
        *(ushort4*)(lds + byte) = h;
    }
    __syncthreads();

    // ---- MFMA scores (kk fully unrolled) ----
    int lrow = l & 15, lk = l >> 4;
    f32x4 acc[4][4];
#pragma unroll
    for (int mt = 0; mt < 4; ++mt)
#pragma unroll
        for (int nt = 0; nt < 4; ++nt) acc[mt][nt] = (f32x4){0.f, 0.f, 0.f, 0.f};

#pragma unroll
    for (int kk = 0; kk < 8; ++kk) {
        short8 afr[4], bfr[4];
#pragma unroll
        for (int nt = 0; nt < 4; ++nt) {
            int ntile = w * 4 + nt;
            bfr[nt] = *(const short8*)&W1p[(((ntile * 8) + kk) * 64 + l) * 8];
        }
#pragma unroll
        for (int mt = 0; mt < 4; ++mt) {
            int row = mt * 16 + lrow;
            int byte = (row * 512 + kk * 64 + lk * 16) ^ ((row & 7) << 4);
            afr[mt] = *(const short8*)(lds + byte);
        }
#pragma unroll
        for (int mt = 0; mt < 4; ++mt)
#pragma unroll
            for (int nt = 0; nt < 4; ++nt)
                acc[mt][nt] = __builtin_amdgcn_mfma_f32_16x16x32_bf16(
                    afr[mt], bfr[nt], acc[mt][nt], 0, 0, 0);
    }

    // ---- epilogue: tanh, .V, reduce over u ----
    float bb[4], vv[4];
#pragma unroll
    for (int nt = 0; nt < 4; ++nt) {
        int u = (w * 4 + nt) * 16 + lrow;
        bb[nt] = pqb[b * U + u];
        vv[nt] = V[u];
    }
#pragma unroll
    for (int mt = 0; mt < 4; ++mt) {
#pragma unroll
        for (int r = 0; r < 4; ++r) {
            float s = 0.f;
#pragma unroll
            for (int nt = 0; nt < 4; ++nt)
                s += fast_tanh(acc[mt][nt][r] + bb[nt]) * vv[nt];
            s += __shfl_xor(s, 1);
            s += __shfl_xor(s, 2);
            s += __shfl_xor(s, 4);
            s += __shfl_xor(s, 8);
            if (lrow == 0) red[w][mt * 16 + lk * 4 + r] = s;
        }
    }
    __syncthreads();
    if (t < ROWS) {  // wave 0
        float s = red[0][t] + red[1][t] + red[2][t] + red[3][t] + bV[0];
        scores[b * S + s0 + t] = s;
        float m = s;
#pragma unroll
        for (int off = 32; off; off >>= 1) m = fmaxf(m, __shfl_xor(m, off));
        float z0 = __expf(s - m);
        wch[t] = z0;
        float z = z0;
#pragma unroll
        for (int off = 32; off; off >>= 1) z += __shfl_xor(z, off);
        if (t == 0) {
            cstats[2 * blockIdx.x] = m;
            cstats[2 * blockIdx.x + 1] = z;
        }
    }
    __syncthreads();

    // partial context from the bf16 LDS copy: thread t owns column t.
    union { uint i; float f; } cv;
    float cacc = 0.f;
#pragma unroll 8
    for (int r = 0; r < ROWS; ++r) {
        int byte = (r * 512 + t * 2) ^ ((r & 7) << 4);
        ushort u = *(const ushort*)(lds + byte);
        cv.i = (uint)u << 16;
        cacc = fmaf(wch[r], cv.f, cacc);
    }
    cpart[(size_t)blockIdx.x * D + t] = cacc;
}

// KC: finisher. 4 blocks per batch (q = quarter).
__global__ void kc_final(const float* __restrict__ scores, const float* __restrict__ cstats,
                         const float* __restrict__ cpart, float* __restrict__ wout,
                         float* __restrict__ ctx) {
    __shared__ float scl[NCHK];
    __shared__ float stats[2];
    __shared__ float part[4][64];
    int b = blockIdx.x >> 2, q = blockIdx.x & 3;
    int t = threadIdx.x;

    if (t < 64) {
        float m = cstats[2 * (b * NCHK + t)];
        float z = cstats[2 * (b * NCHK + t) + 1];
        float M = m;
#pragma unroll
        for (int off = 32; off; off >>= 1) M = fmaxf(M, __shfl_xor(M, off));
        float zz = z * __expf(m - M);
#pragma unroll
        for (int off = 32; off; off >>= 1) zz += __shfl_xor(zz, off);
        scl[t] = __expf(m - M);
        if (t == 0) { stats[0] = M; stats[1] = zz; }
    }
    __syncthreads();
    float M = stats[0];
    float invZ = 1.0f / stats[1];

    int tq = t >> 6, dl = t & 63;
    int d = q * 64 + dl;
    float acc = 0.f;
#pragma unroll
    for (int i = 0; i < 16; ++i) {
        int c = tq * 16 + i;
        acc = fmaf(scl[c], cpart[(size_t)(b * NCHK + c) * D + d], acc);
    }
    part[tq][dl] = acc;

#pragma unroll
    for (int i = 0; i < 4; ++i) {
        int s = q * 1024 + i * 256 + t;
        wout[b * S + s] = __expf(scores[b * S + s] - M) * invZ;
    }
    __syncthreads();
    if (t < 64)
        ctx[b * D + q * 64 + t] =
            (part[0][t] + part[1][t] + part[2][t] + part[3][t]) * invZ;
}

extern "C" void kernel_launch(void* const* d_in, const int* in_sizes, int n_in,
                              void* d_out, int out_size, void* d_ws, size_t ws_size,
                              hipStream_t stream) {
    const float* values = (const float*)d_in[0];
    const float* query  = (const float*)d_in[1];
    const float* W1     = (const float*)d_in[2];
    const float* b1     = (const float*)d_in[3];
    const float* W2     = (const float*)d_in[4];
    const float* b2     = (const float*)d_in[5];
    const float* V      = (const float*)d_in[6];
    const float* bV     = (const float*)d_in[7];

    float* out  = (float*)d_out;
    float* ctx  = out;          // [B, D]
    float* wout = out + B * D;  // [B, S, 1]

    float* ws     = (float*)d_ws;
    float* pqb    = ws;                 // B*U          = 4096
    float* scores = pqb + B * U;        // B*S          = 65536
    float* cstats = scores + B * S;     // 2*B*NCHK     = 2048
    float* cpart  = cstats + 2048;      // B*NCHK*D     = 262144
    ushort* W1p   = (ushort*)(cpart + B * NCHK * D);  // 65536 ushorts

    ka_setup<<<24, 256, 0, stream>>>(query, W2, b2, b1, W1, pqb, W1p);
    kb_scores<<<B * NCHK, 256, 0, stream>>>(values, W1p, pqb, V, bV, scores, cstats, cpart);
    kc_final<<<B * 4, 256, 0, stream>>>(scores, cstats, cpart, wout, ctx);
}